// Round 1
// baseline (1876.127 us; speedup 1.0000x reference)
//
#include <hip/hip_runtime.h>
#include <math.h>

// Problem constants (fixed by reference setup_inputs)
#define BATCH 4
#define SEQ   1024
#define DM    1024       // d_model
#define NH    16         // heads
#define DH    64         // head dim
#define BT    (BATCH*SEQ)   // 4096 GEMM rows

// ---------------------------------------------------------------------------
// GEMM: C[M=4096, N=1024] = A[4096,1024] @ W[1024,1024] (+bias)
// qkv_layout=1: write to (B,H,T,dh) layout; 0: plain row-major + bias.
// 128x128 tile, BK=16, 512 threads, 4x8 per-thread micro-tile,
// register-prefetch pipeline on the global loads.
// ---------------------------------------------------------------------------
#define BM 128
#define BN 128
#define BK 16

__global__ __launch_bounds__(512) void gemm128(
    const float* __restrict__ A, const float* __restrict__ W,
    const float* __restrict__ bias, float* __restrict__ out,
    int qkv_layout)
{
    __shared__ float As[BM][BK + 4];   // [128][20] pad=4 floats: conflict-free scalar reads
    __shared__ float Bs[BK][BN];       // [16][128]

    const int tid = threadIdx.x;
    const int tx  = tid & 15;          // N: 16 groups x (4+4 split cols)
    const int ty  = tid >> 4;          // M: 32 groups x 4 rows
    const int m0  = blockIdx.y * BM;
    const int n0  = blockIdx.x * BN;

    const int la_m = tid >> 2;         // 0..127
    const int la_k = (tid & 3) * 4;    // 0,4,8,12
    const int lb_k = tid >> 5;         // 0..15
    const int lb_n = (tid & 31) * 4;   // 0..124

    const float* aptr = A + (size_t)(m0 + la_m) * DM + la_k;
    const float* bptr = W + (size_t)lb_k * DM + n0 + lb_n;

    float4 pa = *(const float4*)aptr;
    float4 pb = *(const float4*)bptr;

    float acc[4][8];
#pragma unroll
    for (int i = 0; i < 4; ++i)
#pragma unroll
        for (int j = 0; j < 8; ++j) acc[i][j] = 0.f;

    for (int k0 = 0; k0 < DM; k0 += BK) {
        __syncthreads();
        *(float4*)&As[la_m][la_k] = pa;
        *(float4*)&Bs[lb_k][lb_n] = pb;
        __syncthreads();
        if (k0 + BK < DM) {
            pa = *(const float4*)(aptr + k0 + BK);
            pb = *(const float4*)(bptr + (size_t)(k0 + BK) * DM);
        }
#pragma unroll
        for (int kk = 0; kk < BK; ++kk) {
            float av[4];
#pragma unroll
            for (int i = 0; i < 4; ++i) av[i] = As[ty * 4 + i][kk];
            float4 b0 = *(float4*)&Bs[kk][tx * 4];
            float4 b1 = *(float4*)&Bs[kk][64 + tx * 4];
            float bv[8] = {b0.x, b0.y, b0.z, b0.w, b1.x, b1.y, b1.z, b1.w};
#pragma unroll
            for (int i = 0; i < 4; ++i)
#pragma unroll
                for (int j = 0; j < 8; ++j)
                    acc[i][j] = fmaf(av[i], bv[j], acc[i][j]);
        }
    }

    // epilogue
#pragma unroll
    for (int i = 0; i < 4; ++i) {
        int row = m0 + ty * 4 + i;          // 0..4095  (= b*1024 + t)
        int b_  = row >> 10;
        int t_  = row & 1023;
#pragma unroll
        for (int g = 0; g < 2; ++g) {
            int col = n0 + g * 64 + tx * 4; // 0..1023
            float4 r = make_float4(acc[i][g*4+0], acc[i][g*4+1],
                                   acc[i][g*4+2], acc[i][g*4+3]);
            if (qkv_layout) {
                int hh = col >> 6, d = col & 63;
                *(float4*)&out[(((size_t)(b_ * NH + hh)) * SEQ + t_) * DH + d] = r;
            } else {
                float4 bz = *(const float4*)&bias[col];
                r.x += bz.x; r.y += bz.y; r.z += bz.z; r.w += bz.w;
                *(float4*)&out[(size_t)row * DM + col] = r;
            }
        }
    }
}

// ---------------------------------------------------------------------------
// Flash-style causal attention with relative position bias.
// Grid: (q_tile=16, bh=64). Block: 256 threads. Each block: 64 q-rows.
// Thread (row, sub): sub in 0..3 splits the 64 k-cols / 64 out-dims.
// logits = (q.k + rpb[h][1023-i+j]) / 64, causal; online softmax.
// K LDS buffer is reused to hold P after the logits phase (saves 16 KB).
// ---------------------------------------------------------------------------
__global__ __launch_bounds__(256) void attn_kernel(
    const float* __restrict__ q, const float* __restrict__ k,
    const float* __restrict__ v, const float* __restrict__ rpb,
    float* __restrict__ ao)
{
    const int qt  = blockIdx.x;       // 0..15
    const int bh  = blockIdx.y;       // 0..63
    const int b_  = bh >> 4;
    const int h_  = bh & 15;
    const int tid = threadIdx.x;
    const int row = tid >> 2;         // 0..63
    const int sub = tid & 3;          // 0..3
    const int i   = qt * 64 + row;    // global query row

    __shared__ float kp_s[64][68];    // K tile, then reused as P
    __shared__ float v_s[64][68];

    const size_t base = (size_t)bh * SEQ * DH;

    // Q row -> registers (64 floats)
    float4 qreg[16];
    {
        const float* qrow = q + base + (size_t)i * DH;
#pragma unroll
        for (int w = 0; w < 16; ++w) qreg[w] = *(const float4*)&qrow[w * 4];
    }

    float m = -INFINITY, l = 0.f;
    float acc[16];
#pragma unroll
    for (int d0 = 0; d0 < 16; ++d0) acc[d0] = 0.f;

    const float* rpb_h = rpb + h_ * SEQ;
    const float inv_dh = 1.0f / 64.0f;

    for (int kt = 0; kt <= qt; ++kt) {
        __syncthreads();   // previous tile's P/V fully consumed
        {
            const float* kbase = k + base + (size_t)kt * 64 * DH;
            const float* vbase = v + base + (size_t)kt * 64 * DH;
            for (int idx = tid; idx < 64 * 16; idx += 256) {
                int r = idx >> 4, c = (idx & 15) * 4;
                *(float4*)&kp_s[r][c] = *(const float4*)&kbase[r * DH + c];
                *(float4*)&v_s[r][c]  = *(const float4*)&vbase[r * DH + c];
            }
        }
        __syncthreads();

        // ---- logits: 16 columns per thread ----
        float s[16];
#pragma unroll
        for (int jj = 0; jj < 16; ++jj) s[jj] = 0.f;
#pragma unroll
        for (int w = 0; w < 16; ++w) {
            float4 qv = qreg[w];
#pragma unroll
            for (int jj = 0; jj < 16; ++jj) {
                float4 kv = *(const float4*)&kp_s[sub * 16 + jj][w * 4];
                s[jj] = fmaf(qv.x, kv.x, s[jj]);
                s[jj] = fmaf(qv.y, kv.y, s[jj]);
                s[jj] = fmaf(qv.z, kv.z, s[jj]);
                s[jj] = fmaf(qv.w, kv.w, s[jj]);
            }
        }
        const int j0 = kt * 64 + sub * 16;
        float tmax = -INFINITY;
#pragma unroll
        for (int jj = 0; jj < 16; ++jj) {
            int j = j0 + jj;
            if (j <= i) {
                float val = (s[jj] + rpb_h[1023 - i + j]) * inv_dh;
                s[jj] = val;
                tmax = fmaxf(tmax, val);
            } else {
                s[jj] = -INFINITY;
            }
        }
        // row-max across the 4 sub lanes (contiguous lanes, width-4 groups)
        tmax = fmaxf(tmax, __shfl_xor(tmax, 1, 4));
        tmax = fmaxf(tmax, __shfl_xor(tmax, 2, 4));
        float mn   = fmaxf(m, tmax);       // finite: every tile has >=1 valid col
        float corr = __expf(m - mn);       // first tile: exp(-inf)=0
        float p[16];
        float psum = 0.f;
#pragma unroll
        for (int jj = 0; jj < 16; ++jj) {
            p[jj] = __expf(s[jj] - mn);    // masked: exp(-inf)=0
            psum += p[jj];
        }
        psum += __shfl_xor(psum, 1, 4);
        psum += __shfl_xor(psum, 2, 4);
        l = l * corr + psum;
        m = mn;
#pragma unroll
        for (int d0 = 0; d0 < 16; ++d0) acc[d0] *= corr;

        __syncthreads();   // all waves done reading K before P overwrites it
#pragma unroll
        for (int jj = 0; jj < 16; ++jj) kp_s[row][sub * 16 + jj] = p[jj];
        // P written/read by the same wave's lanes of this row -> no barrier needed

        // ---- PV: out dims sub*16 .. sub*16+15 ----
#pragma unroll 8
        for (int kk = 0; kk < 64; ++kk) {
            float pp = kp_s[row][kk];
            const float* vr = &v_s[kk][sub * 16];
            float4 v0 = *(const float4*)&vr[0];
            float4 v1 = *(const float4*)&vr[4];
            float4 v2 = *(const float4*)&vr[8];
            float4 v3 = *(const float4*)&vr[12];
            acc[0]  = fmaf(pp, v0.x, acc[0]);  acc[1]  = fmaf(pp, v0.y, acc[1]);
            acc[2]  = fmaf(pp, v0.z, acc[2]);  acc[3]  = fmaf(pp, v0.w, acc[3]);
            acc[4]  = fmaf(pp, v1.x, acc[4]);  acc[5]  = fmaf(pp, v1.y, acc[5]);
            acc[6]  = fmaf(pp, v1.z, acc[6]);  acc[7]  = fmaf(pp, v1.w, acc[7]);
            acc[8]  = fmaf(pp, v2.x, acc[8]);  acc[9]  = fmaf(pp, v2.y, acc[9]);
            acc[10] = fmaf(pp, v2.z, acc[10]); acc[11] = fmaf(pp, v2.w, acc[11]);
            acc[12] = fmaf(pp, v3.x, acc[12]); acc[13] = fmaf(pp, v3.y, acc[13]);
            acc[14] = fmaf(pp, v3.z, acc[14]); acc[15] = fmaf(pp, v3.w, acc[15]);
        }
    }

    // epilogue: attn_out in (b, t, h*64+d) layout for the output projection
    float invl = 1.f / l;
    float* orow = ao + ((size_t)(b_ * SEQ + i)) * DM + h_ * DH + sub * 16;
#pragma unroll
    for (int w = 0; w < 4; ++w) {
        float4 r = make_float4(acc[w*4+0] * invl, acc[w*4+1] * invl,
                               acc[w*4+2] * invl, acc[w*4+3] * invl);
        *(float4*)&orow[w * 4] = r;
    }
}

// ---------------------------------------------------------------------------
extern "C" void kernel_launch(void* const* d_in, const int* in_sizes, int n_in,
                              void* d_out, int out_size, void* d_ws, size_t ws_size,
                              hipStream_t stream)
{
    (void)in_sizes; (void)n_in; (void)out_size; (void)ws_size;
    const float* x   = (const float*)d_in[0];
    const float* Wq  = (const float*)d_in[1];
    const float* Wk  = (const float*)d_in[2];
    const float* Wv  = (const float*)d_in[3];
    const float* Wo  = (const float*)d_in[4];
    const float* bo  = (const float*)d_in[5];
    const float* rpb = (const float*)d_in[6];
    float* out = (float*)d_out;

    const size_t NELT = (size_t)BT * DM;   // 4,194,304 floats = 16 MB
    float* q  = (float*)d_ws;
    float* kk = q  + NELT;
    float* vv = kk + NELT;
    float* ao = vv + NELT;

    dim3 ggrid(BN == 128 ? DM / BN : 8, BT / BM);   // (8, 32)
    gemm128<<<ggrid, 512, 0, stream>>>(x,  Wq, nullptr, q,  1);
    gemm128<<<ggrid, 512, 0, stream>>>(x,  Wk, nullptr, kk, 1);
    gemm128<<<ggrid, 512, 0, stream>>>(x,  Wv, nullptr, vv, 1);
    attn_kernel<<<dim3(SEQ / 64, BATCH * NH), 256, 0, stream>>>(q, kk, vv, rpb, ao);
    gemm128<<<ggrid, 512, 0, stream>>>(ao, Wo, bo, out, 0);
}

// Round 5
// 613.582 us; speedup vs baseline: 3.0577x; 3.0577x over previous
//
#include <hip/hip_runtime.h>
#include <math.h>

// Problem constants (fixed by reference setup_inputs)
#define BATCH 4
#define SEQ   1024
#define DM    1024       // d_model
#define NH    16         // heads
#define DH    64         // head dim
#define BT    (BATCH*SEQ)   // 4096 GEMM rows

typedef _Float16 f16x8 __attribute__((ext_vector_type(8)));
typedef _Float16 f16x4 __attribute__((ext_vector_type(4)));
typedef float    f32x4 __attribute__((ext_vector_type(4)));

// ---------------------------------------------------------------------------
// GEMM: C[4096,1024] = A[4096,1024] @ W[1024,1024]
// MODE 0: fp32 out, row-major, + bias (final projection)
// MODE 1: f16 out in (B,H,T,dh) layout, scaled by `scale` (QKV projections)
// ---------------------------------------------------------------------------
#define BM 128
#define BN 128
#define BK 16

template<int MODE>
__global__ __launch_bounds__(512) void gemm128(
    const float* __restrict__ A, const float* __restrict__ W,
    const float* __restrict__ bias, void* __restrict__ outp, float scale)
{
    __shared__ float As[BM][BK + 4];
    __shared__ float Bs[BK][BN];

    const int tid = threadIdx.x;
    const int tx  = tid & 15;
    const int ty  = tid >> 4;
    const int m0  = blockIdx.y * BM;
    const int n0  = blockIdx.x * BN;

    const int la_m = tid >> 2;
    const int la_k = (tid & 3) * 4;
    const int lb_k = tid >> 5;
    const int lb_n = (tid & 31) * 4;

    const float* aptr = A + (size_t)(m0 + la_m) * DM + la_k;
    const float* bptr = W + (size_t)lb_k * DM + n0 + lb_n;

    float4 pa = *(const float4*)aptr;
    float4 pb = *(const float4*)bptr;

    float acc[4][8];
#pragma unroll
    for (int i = 0; i < 4; ++i)
#pragma unroll
        for (int j = 0; j < 8; ++j) acc[i][j] = 0.f;

    for (int k0 = 0; k0 < DM; k0 += BK) {
        __syncthreads();
        *(float4*)&As[la_m][la_k] = pa;
        *(float4*)&Bs[lb_k][lb_n] = pb;
        __syncthreads();
        if (k0 + BK < DM) {
            pa = *(const float4*)(aptr + k0 + BK);
            pb = *(const float4*)(bptr + (size_t)(k0 + BK) * DM);
        }
#pragma unroll
        for (int kk = 0; kk < BK; ++kk) {
            float av[4];
#pragma unroll
            for (int i = 0; i < 4; ++i) av[i] = As[ty * 4 + i][kk];
            float4 b0 = *(float4*)&Bs[kk][tx * 4];
            float4 b1 = *(float4*)&Bs[kk][64 + tx * 4];
            float bv[8] = {b0.x, b0.y, b0.z, b0.w, b1.x, b1.y, b1.z, b1.w};
#pragma unroll
            for (int i = 0; i < 4; ++i)
#pragma unroll
                for (int j = 0; j < 8; ++j)
                    acc[i][j] = fmaf(av[i], bv[j], acc[i][j]);
        }
    }

#pragma unroll
    for (int i = 0; i < 4; ++i) {
        int row = m0 + ty * 4 + i;
        int b_  = row >> 10;
        int t_  = row & 1023;
#pragma unroll
        for (int g = 0; g < 2; ++g) {
            int col = n0 + g * 64 + tx * 4;
            if (MODE == 1) {
                _Float16* out = (_Float16*)outp;
                int hh = col >> 6, d = col & 63;
                f16x4 r4;
                r4[0] = (_Float16)(acc[i][g*4+0] * scale);
                r4[1] = (_Float16)(acc[i][g*4+1] * scale);
                r4[2] = (_Float16)(acc[i][g*4+2] * scale);
                r4[3] = (_Float16)(acc[i][g*4+3] * scale);
                *(f16x4*)&out[(((size_t)(b_ * NH + hh)) * SEQ + t_) * DH + d] = r4;
            } else {
                float* out = (float*)outp;
                float4 r = make_float4(acc[i][g*4+0], acc[i][g*4+1],
                                       acc[i][g*4+2], acc[i][g*4+3]);
                float4 bz = *(const float4*)&bias[col];
                r.x += bz.x; r.y += bz.y; r.z += bz.z; r.w += bz.w;
                *(float4*)&out[(size_t)row * DM + col] = r;
            }
        }
    }
}

// ---------------------------------------------------------------------------
// V [bh][1024 t][64 d] f16  ->  Vt [bh][64 d][1024 t] f16
// ---------------------------------------------------------------------------
__global__ __launch_bounds__(256) void vtranspose(const _Float16* __restrict__ V,
                                                  _Float16* __restrict__ Vt)
{
    __shared__ _Float16 tile[64][72];
    const int bh = blockIdx.y;
    const int t0 = blockIdx.x * 64;
    const int tid = threadIdx.x;
    const int r = tid >> 3;          // 0..31
    const int c = (tid & 7) * 8;     // 0..56
    const size_t base = (size_t)bh * (SEQ * DH);
#pragma unroll
    for (int p = 0; p < 2; ++p) {
        int row = r + p * 32;
        *(f16x8*)&tile[row][c] = *(const f16x8*)&V[base + (size_t)(t0 + row) * DH + c];
    }
    __syncthreads();
#pragma unroll
    for (int p = 0; p < 2; ++p) {
        int d = r + p * 32;
        f16x8 vv;
#pragma unroll
        for (int i = 0; i < 8; ++i) vv[i] = tile[c + i][d];
        *(f16x8*)&Vt[base + (size_t)d * SEQ + t0 + c] = vv;
    }
}

// ---------------------------------------------------------------------------
// Flash attention, f16 MFMA (16x16x32), causal + rel-pos bias.
// Grid (8 pairs, 64 bh), 256 threads = 4 independent waves (NO barriers).
// Block processes q-tiles pr and 15-pr (uniform 17 kv-tiles of work).
// Wave w owns 16 q-rows. C/D layout: col=lane&15, row=(lane>>4)*4+reg.
// A/B fragments use a consistent slot->k mapping (k = kg*8+i within chunk),
// which is correct for any HW k-grouping as long as A and B agree.
// ---------------------------------------------------------------------------
__global__ __launch_bounds__(256) void attn_mfma(
    const _Float16* __restrict__ Q,   // [bh][1024][64], pre-scaled by 1/64
    const _Float16* __restrict__ K,   // [bh][1024][64]
    const _Float16* __restrict__ Vt,  // [bh][64][1024]
    const float* __restrict__ rpb,    // [16][1024]
    float* __restrict__ ao)           // [b][t][h*64+d] fp32
{
    const int pr  = blockIdx.x;       // 0..7
    const int bh  = blockIdx.y;       // 0..63
    const int b_  = bh >> 4;
    const int h_  = bh & 15;
    const int tid = threadIdx.x;
    const int w   = tid >> 6;         // wave 0..3
    const int ln  = tid & 63;
    const int l15 = ln & 15;
    const int lg  = ln >> 4;          // 0..3

    __shared__ _Float16 Pb[4][16][72];   // per-wave P buffer (row stride 144B)

    const size_t qkb = (size_t)bh * (SEQ * DH);
    const float* rpb_h = rpb + h_ * SEQ;

#pragma unroll 1
    for (int half = 0; half < 2; ++half) {
        const int qt  = half ? (15 - pr) : pr;
        const int qr0 = qt * 64 + w * 16;

        // Q A-fragments (held in registers for the whole kv loop)
        f16x8 qa0, qa1;
        {
            const _Float16* qp = Q + qkb + (size_t)(qr0 + l15) * DH + lg * 8;
            qa0 = *(const f16x8*)qp;
            qa1 = *(const f16x8*)(qp + 32);
        }
        f32x4 acc[4];
        float mrow[4], lrow[4];
#pragma unroll
        for (int t = 0; t < 4; ++t) {
            acc[t] = (f32x4){0.f, 0.f, 0.f, 0.f};
            mrow[t] = -INFINITY;
            lrow[t] = 0.f;
        }
        const int ibase = qr0 + lg * 4;           // q row for reg r is ibase + r

#pragma unroll 1
        for (int kt = 0; kt <= qt; ++kt) {
            // ---- S = Q K^T (4 kv sub-tiles of 16) ----
            const _Float16* kp = K + qkb + (size_t)(kt * 64 + l15) * DH + lg * 8;
            f32x4 s[4];
#pragma unroll
            for (int st = 0; st < 4; ++st) {
                f16x8 kb0 = *(const f16x8*)(kp + st * 16 * DH);
                f16x8 kb1 = *(const f16x8*)(kp + st * 16 * DH + 32);
                f32x4 z = (f32x4){0.f, 0.f, 0.f, 0.f};
                z = __builtin_amdgcn_mfma_f32_16x16x32_f16(qa0, kb0, z, 0, 0, 0);
                z = __builtin_amdgcn_mfma_f32_16x16x32_f16(qa1, kb1, z, 0, 0, 0);
                s[st] = z;
            }
            // ---- bias + causal mask + tile max ----
            // idx = 1023 - i + j ; masked <=> idx > 1023 (j > i). idx >= 0 always.
            const int bidx = 1023 - ibase + l15 + kt * 64;
            float tm[4] = {-INFINITY, -INFINITY, -INFINITY, -INFINITY};
#pragma unroll
            for (int st = 0; st < 4; ++st)
#pragma unroll
                for (int r = 0; r < 4; ++r) {
                    int idx = bidx + st * 16 - r;
                    float bv = rpb_h[idx <= 1023 ? idx : 1023];
                    float val = (idx <= 1023) ? fmaf(bv, 0.015625f, s[st][r]) : -INFINITY;
                    s[st][r] = val;
                    tm[r] = fmaxf(tm[r], val);
                }
            // ---- online softmax (reduce over 16 kv lanes) ----
#pragma unroll
            for (int r = 0; r < 4; ++r) {
                tm[r] = fmaxf(tm[r], __shfl_xor(tm[r], 1, 16));
                tm[r] = fmaxf(tm[r], __shfl_xor(tm[r], 2, 16));
                tm[r] = fmaxf(tm[r], __shfl_xor(tm[r], 4, 16));
                tm[r] = fmaxf(tm[r], __shfl_xor(tm[r], 8, 16));
            }
            float corr[4], psum[4];
#pragma unroll
            for (int r = 0; r < 4; ++r) {
                float mn = fmaxf(mrow[r], tm[r]);
                corr[r]  = __expf(mrow[r] - mn);
                mrow[r]  = mn;
                psum[r]  = 0.f;
            }
#pragma unroll
            for (int st = 0; st < 4; ++st)
#pragma unroll
                for (int r = 0; r < 4; ++r) {
                    float p = __expf(s[st][r] - mrow[r]);
                    s[st][r] = p;
                    psum[r] += p;
                }
#pragma unroll
            for (int r = 0; r < 4; ++r) {
                psum[r] += __shfl_xor(psum[r], 1, 16);
                psum[r] += __shfl_xor(psum[r], 2, 16);
                psum[r] += __shfl_xor(psum[r], 4, 16);
                psum[r] += __shfl_xor(psum[r], 8, 16);
                lrow[r] = lrow[r] * corr[r] + psum[r];
            }
#pragma unroll
            for (int t = 0; t < 4; ++t) {
                acc[t][0] *= corr[0]; acc[t][1] *= corr[1];
                acc[t][2] *= corr[2]; acc[t][3] *= corr[3];
            }
            // ---- P -> per-wave LDS (S layout -> A-frag layout) ----
#pragma unroll
            for (int st = 0; st < 4; ++st)
#pragma unroll
                for (int r = 0; r < 4; ++r)
                    Pb[w][lg * 4 + r][st * 16 + l15] = (_Float16)s[st][r];
            // ---- PV: acc[dt] += P[16x64] * V[64x16] ----
            f16x8 pa0 = *(const f16x8*)&Pb[w][l15][lg * 8];
            f16x8 pa1 = *(const f16x8*)&Pb[w][l15][32 + lg * 8];
            const _Float16* vp = Vt + qkb + (size_t)l15 * SEQ + kt * 64 + lg * 8;
#pragma unroll
            for (int dt = 0; dt < 4; ++dt) {
                f16x8 vb0 = *(const f16x8*)(vp + dt * 16 * SEQ);
                f16x8 vb1 = *(const f16x8*)(vp + dt * 16 * SEQ + 32);
                acc[dt] = __builtin_amdgcn_mfma_f32_16x16x32_f16(pa0, vb0, acc[dt], 0, 0, 0);
                acc[dt] = __builtin_amdgcn_mfma_f32_16x16x32_f16(pa1, vb1, acc[dt], 0, 0, 0);
            }
        }
        // ---- epilogue ----
        float* aop = ao + ((size_t)b_ * SEQ + ibase) * DM + h_ * DH + l15;
#pragma unroll
        for (int r = 0; r < 4; ++r) {
            float inv = 1.f / lrow[r];
#pragma unroll
            for (int dt = 0; dt < 4; ++dt)
                aop[(size_t)r * DM + dt * 16] = acc[dt][r] * inv;
        }
    }
}

// ---------------------------------------------------------------------------
extern "C" void kernel_launch(void* const* d_in, const int* in_sizes, int n_in,
                              void* d_out, int out_size, void* d_ws, size_t ws_size,
                              hipStream_t stream)
{
    (void)in_sizes; (void)n_in; (void)out_size; (void)ws_size;
    const float* x   = (const float*)d_in[0];
    const float* Wq  = (const float*)d_in[1];
    const float* Wk  = (const float*)d_in[2];
    const float* Wv  = (const float*)d_in[3];
    const float* Wo  = (const float*)d_in[4];
    const float* bo  = (const float*)d_in[5];
    const float* rpb = (const float*)d_in[6];
    float* out = (float*)d_out;

    char* ws = (char*)d_ws;
    _Float16* q  = (_Float16*)(ws);                  // 8 MB
    _Float16* k  = (_Float16*)(ws + (8u  << 20));    // 8 MB
    _Float16* v  = (_Float16*)(ws + (16u << 20));    // 8 MB
    _Float16* vt = (_Float16*)(ws + (24u << 20));    // 8 MB
    float*    ao = (float*)   (ws + (32u << 20));    // 16 MB

    dim3 ggrid(DM / BN, BT / BM);   // (8, 32)
    gemm128<1><<<ggrid, 512, 0, stream>>>(x, Wq, nullptr, q, 0.015625f);  // Q/64
    gemm128<1><<<ggrid, 512, 0, stream>>>(x, Wk, nullptr, k, 1.0f);
    gemm128<1><<<ggrid, 512, 0, stream>>>(x, Wv, nullptr, v, 1.0f);
    vtranspose<<<dim3(SEQ / 64, BATCH * NH), 256, 0, stream>>>(v, vt);
    attn_mfma<<<dim3(8, BATCH * NH), 256, 0, stream>>>(q, k, vt, rpb, ao);
    gemm128<0><<<ggrid, 512, 0, stream>>>(ao, Wo, bo, out, 1.0f);
}

// Round 6
// 259.725 us; speedup vs baseline: 7.2235x; 2.3624x over previous
//
#include <hip/hip_runtime.h>
#include <math.h>

// Problem constants (fixed by reference setup_inputs)
#define BATCH 4
#define SEQ   1024
#define DM    1024       // d_model
#define NH    16         // heads
#define DH    64         // head dim
#define BT    (BATCH*SEQ)   // 4096 GEMM rows

typedef _Float16 f16x8 __attribute__((ext_vector_type(8)));
typedef _Float16 f16x4 __attribute__((ext_vector_type(4)));
typedef float    f32x4 __attribute__((ext_vector_type(4)));

// async global->LDS, 16B per lane; LDS dest is wave-uniform base + lane*16
#define GLL16(ldsdst, gsrc) \
  __builtin_amdgcn_global_load_lds((const __attribute__((address_space(1))) void*)(gsrc), \
                                   (__attribute__((address_space(3))) void*)(ldsdst), 16, 0, 0)

// ---------------------------------------------------------------------------
// fp32 -> f16 elementwise (x conversion), float4 -> f16x4
// ---------------------------------------------------------------------------
__global__ __launch_bounds__(256) void cvt_x(const float* __restrict__ x,
                                             _Float16* __restrict__ xh, int nquads)
{
    int i = blockIdx.x * blockDim.x + threadIdx.x;
    for (; i < nquads; i += gridDim.x * blockDim.x) {
        float4 f = ((const float4*)x)[i];
        f16x4 h;
        h[0] = (_Float16)f.x; h[1] = (_Float16)f.y;
        h[2] = (_Float16)f.z; h[3] = (_Float16)f.w;
        ((f16x4*)xh)[i] = h;
    }
}

// ---------------------------------------------------------------------------
// W [1024 k][1024 n] fp32  ->  Wt [1024 n][1024 k] f16   (4 weights, grid.z)
// ---------------------------------------------------------------------------
__global__ __launch_bounds__(256) void cvt_wT(
    const float* __restrict__ W0, const float* __restrict__ W1,
    const float* __restrict__ W2, const float* __restrict__ W3,
    _Float16* __restrict__ T0, _Float16* __restrict__ T1,
    _Float16* __restrict__ T2, _Float16* __restrict__ T3)
{
    __shared__ _Float16 tile[64][72];
    const int z = blockIdx.z;
    const float* W = (z == 0) ? W0 : (z == 1) ? W1 : (z == 2) ? W2 : W3;
    _Float16*    T = (z == 0) ? T0 : (z == 1) ? T1 : (z == 2) ? T2 : T3;
    const int n0 = blockIdx.x * 64;
    const int k0 = blockIdx.y * 64;
    const int tid = threadIdx.x;
#pragma unroll
    for (int p = 0; p < 4; ++p) {
        int r = (tid >> 4) + p * 16;           // k within tile
        int c = (tid & 15) * 4;                // n within tile
        float4 f = *(const float4*)&W[(size_t)(k0 + r) * DM + n0 + c];
        f16x4 h;
        h[0] = (_Float16)f.x; h[1] = (_Float16)f.y;
        h[2] = (_Float16)f.z; h[3] = (_Float16)f.w;
        *(f16x4*)&tile[r][c] = h;
    }
    __syncthreads();
#pragma unroll
    for (int p = 0; p < 2; ++p) {
        int nr = (tid >> 3) + p * 32;          // n within tile
        int kc = (tid & 7) * 8;                // k within tile
        f16x8 vv;
#pragma unroll
        for (int i = 0; i < 8; ++i) vv[i] = tile[kc + i][nr];
        *(f16x8*)&T[(size_t)(n0 + nr) * DM + k0 + kc] = vv;
    }
}

// ---------------------------------------------------------------------------
// f16 MFMA GEMM, m97 structure: 128x128 tile, BK=32, 4 waves, 4x4 16x16x32
// frags per wave, global_load_lds staging (linear LDS), 2-barrier K-loop.
// A [4096][1024] f16 row-major; Bt [N][1024] f16 (transposed weight).
// MODE 1: QKV fused (grid.x = 24: 8 n-tiles each for q,k,v), f16 out in
//         (B,H,T,dh) layout, q scaled by 1/64.
// MODE 0: Wo (grid.x = 8), fp32 out row-major + bias.
// ---------------------------------------------------------------------------
template<int MODE>
__global__ __launch_bounds__(256) void gemm_mfma(
    const _Float16* __restrict__ A,
    const _Float16* __restrict__ B0, const _Float16* __restrict__ B1,
    const _Float16* __restrict__ B2,
    void* __restrict__ o0, void* __restrict__ o1, void* __restrict__ o2,
    const float* __restrict__ bias)
{
    __shared__ _Float16 As[128 * 32];
    __shared__ _Float16 Bs[128 * 32];

    const int tid = threadIdx.x;
    const int w   = tid >> 6;          // wave 0..3
    const int ln  = tid & 63;
    const int l15 = ln & 15;
    const int lg  = ln >> 4;           // 0..3
    const int wr  = w >> 1;            // wave row quadrant
    const int wc  = w & 1;             // wave col quadrant
    const int which = MODE ? (blockIdx.x >> 3) : 0;     // 0:q 1:k 2:v
    const int nl  = (blockIdx.x & 7) * 128;
    const int m0  = blockIdx.y * 128;

    const _Float16* Bt = (which == 0) ? B0 : (which == 1 ? B1 : B2);

    // staging: wave w covers rows w*32..w*32+31 of each tile (2 issues each)
    const int srow = ln >> 2;          // 0..15
    const int scol = (ln & 3) * 8;     // halves
    const _Float16* ga = A  + (size_t)(m0 + w * 32 + srow) * DM + scol;
    const _Float16* gb = Bt + (size_t)(nl + w * 32 + srow) * DM + scol;
    _Float16* la0 = &As[(w * 32 +  0) * 32];
    _Float16* la1 = &As[(w * 32 + 16) * 32];
    _Float16* lb0 = &Bs[(w * 32 +  0) * 32];
    _Float16* lb1 = &Bs[(w * 32 + 16) * 32];

    f32x4 acc[4][4];
#pragma unroll
    for (int i = 0; i < 4; ++i)
#pragma unroll
        for (int j = 0; j < 4; ++j) acc[i][j] = (f32x4){0.f, 0.f, 0.f, 0.f};

    for (int k0 = 0; k0 < DM; k0 += 32) {
        GLL16(la0, ga + k0);
        GLL16(la1, ga + k0 + (size_t)16 * DM);
        GLL16(lb0, gb + k0);
        GLL16(lb1, gb + k0 + (size_t)16 * DM);
        __syncthreads();               // drains vmcnt: tiles staged

        f16x8 af[4], bf[4];
#pragma unroll
        for (int i = 0; i < 4; ++i)
            af[i] = *(const f16x8*)&As[(wr * 64 + i * 16 + l15) * 32 + lg * 8];
#pragma unroll
        for (int j = 0; j < 4; ++j)
            bf[j] = *(const f16x8*)&Bs[(wc * 64 + j * 16 + l15) * 32 + lg * 8];
#pragma unroll
        for (int i = 0; i < 4; ++i)
#pragma unroll
            for (int j = 0; j < 4; ++j)
                acc[i][j] = __builtin_amdgcn_mfma_f32_16x16x32_f16(af[i], bf[j], acc[i][j], 0, 0, 0);
        __syncthreads();               // all reads done before next overwrite
    }

    if (MODE == 1) {
        _Float16* outp = (which == 0) ? (_Float16*)o0
                        : (which == 1) ? (_Float16*)o1 : (_Float16*)o2;
        const float scale = (which == 0) ? 0.015625f : 1.0f;   // Q /= 64
#pragma unroll
        for (int i = 0; i < 4; ++i)
#pragma unroll
            for (int j = 0; j < 4; ++j) {
                int n  = nl + wc * 64 + j * 16 + l15;
                int hh = n >> 6, d = n & 63;
#pragma unroll
                for (int r = 0; r < 4; ++r) {
                    int m  = m0 + wr * 64 + i * 16 + lg * 4 + r;
                    int b_ = m >> 10, t_ = m & 1023;
                    outp[(((size_t)(b_ * NH + hh)) * SEQ + t_) * DH + d] =
                        (_Float16)(acc[i][j][r] * scale);
                }
            }
    } else {
        float* outp = (float*)o0;
#pragma unroll
        for (int i = 0; i < 4; ++i)
#pragma unroll
            for (int j = 0; j < 4; ++j) {
                int n = nl + wc * 64 + j * 16 + l15;
                float bz = bias[n];
#pragma unroll
                for (int r = 0; r < 4; ++r) {
                    int m = m0 + wr * 64 + i * 16 + lg * 4 + r;
                    outp[(size_t)m * DM + n] = acc[i][j][r] + bz;
                }
            }
    }
}

// ---------------------------------------------------------------------------
// V [bh][1024 t][64 d] f16  ->  Vt [bh][64 d][1024 t] f16
// ---------------------------------------------------------------------------
__global__ __launch_bounds__(256) void vtranspose(const _Float16* __restrict__ V,
                                                  _Float16* __restrict__ Vt)
{
    __shared__ _Float16 tile[64][72];
    const int bh = blockIdx.y;
    const int t0 = blockIdx.x * 64;
    const int tid = threadIdx.x;
    const int r = tid >> 3;          // 0..31
    const int c = (tid & 7) * 8;     // 0..56
    const size_t base = (size_t)bh * (SEQ * DH);
#pragma unroll
    for (int p = 0; p < 2; ++p) {
        int row = r + p * 32;
        *(f16x8*)&tile[row][c] = *(const f16x8*)&V[base + (size_t)(t0 + row) * DH + c];
    }
    __syncthreads();
#pragma unroll
    for (int p = 0; p < 2; ++p) {
        int d = r + p * 32;
        f16x8 vv;
#pragma unroll
        for (int i = 0; i < 8; ++i) vv[i] = tile[c + i][d];
        *(f16x8*)&Vt[base + (size_t)d * SEQ + t0 + c] = vv;
    }
}

// ---------------------------------------------------------------------------
// Flash attention, f16 MFMA (16x16x32), causal + rel-pos bias.
// Grid (8 pairs, 64 bh), 256 threads = 4 independent waves (NO barriers).
// Output ao now f16 (feeds the f16 MFMA Wo GEMM).
// ---------------------------------------------------------------------------
__global__ __launch_bounds__(256) void attn_mfma(
    const _Float16* __restrict__ Q,   // [bh][1024][64], pre-scaled by 1/64
    const _Float16* __restrict__ K,   // [bh][1024][64]
    const _Float16* __restrict__ Vt,  // [bh][64][1024]
    const float* __restrict__ rpb,    // [16][1024]
    _Float16* __restrict__ ao)        // [b][t][h*64+d] f16
{
    const int pr  = blockIdx.x;       // 0..7
    const int bh  = blockIdx.y;       // 0..63
    const int b_  = bh >> 4;
    const int h_  = bh & 15;
    const int tid = threadIdx.x;
    const int w   = tid >> 6;         // wave 0..3
    const int ln  = tid & 63;
    const int l15 = ln & 15;
    const int lg  = ln >> 4;          // 0..3

    __shared__ _Float16 Pb[4][16][72];   // per-wave P buffer

    const size_t qkb = (size_t)bh * (SEQ * DH);
    const float* rpb_h = rpb + h_ * SEQ;

#pragma unroll 1
    for (int half = 0; half < 2; ++half) {
        const int qt  = half ? (15 - pr) : pr;
        const int qr0 = qt * 64 + w * 16;

        f16x8 qa0, qa1;
        {
            const _Float16* qp = Q + qkb + (size_t)(qr0 + l15) * DH + lg * 8;
            qa0 = *(const f16x8*)qp;
            qa1 = *(const f16x8*)(qp + 32);
        }
        f32x4 acc[4];
        float mrow[4], lrow[4];
#pragma unroll
        for (int t = 0; t < 4; ++t) {
            acc[t] = (f32x4){0.f, 0.f, 0.f, 0.f};
            mrow[t] = -INFINITY;
            lrow[t] = 0.f;
        }
        const int ibase = qr0 + lg * 4;

#pragma unroll 1
        for (int kt = 0; kt <= qt; ++kt) {
            const _Float16* kp = K + qkb + (size_t)(kt * 64 + l15) * DH + lg * 8;
            f32x4 s[4];
#pragma unroll
            for (int st = 0; st < 4; ++st) {
                f16x8 kb0 = *(const f16x8*)(kp + st * 16 * DH);
                f16x8 kb1 = *(const f16x8*)(kp + st * 16 * DH + 32);
                f32x4 z = (f32x4){0.f, 0.f, 0.f, 0.f};
                z = __builtin_amdgcn_mfma_f32_16x16x32_f16(qa0, kb0, z, 0, 0, 0);
                z = __builtin_amdgcn_mfma_f32_16x16x32_f16(qa1, kb1, z, 0, 0, 0);
                s[st] = z;
            }
            const int bidx = 1023 - ibase + l15 + kt * 64;
            float tm[4] = {-INFINITY, -INFINITY, -INFINITY, -INFINITY};
#pragma unroll
            for (int st = 0; st < 4; ++st)
#pragma unroll
                for (int r = 0; r < 4; ++r) {
                    int idx = bidx + st * 16 - r;
                    float bv = rpb_h[idx <= 1023 ? idx : 1023];
                    float val = (idx <= 1023) ? fmaf(bv, 0.015625f, s[st][r]) : -INFINITY;
                    s[st][r] = val;
                    tm[r] = fmaxf(tm[r], val);
                }
#pragma unroll
            for (int r = 0; r < 4; ++r) {
                tm[r] = fmaxf(tm[r], __shfl_xor(tm[r], 1, 16));
                tm[r] = fmaxf(tm[r], __shfl_xor(tm[r], 2, 16));
                tm[r] = fmaxf(tm[r], __shfl_xor(tm[r], 4, 16));
                tm[r] = fmaxf(tm[r], __shfl_xor(tm[r], 8, 16));
            }
            float corr[4], psum[4];
#pragma unroll
            for (int r = 0; r < 4; ++r) {
                float mn = fmaxf(mrow[r], tm[r]);
                corr[r]  = __expf(mrow[r] - mn);
                mrow[r]  = mn;
                psum[r]  = 0.f;
            }
#pragma unroll
            for (int st = 0; st < 4; ++st)
#pragma unroll
                for (int r = 0; r < 4; ++r) {
                    float p = __expf(s[st][r] - mrow[r]);
                    s[st][r] = p;
                    psum[r] += p;
                }
#pragma unroll
            for (int r = 0; r < 4; ++r) {
                psum[r] += __shfl_xor(psum[r], 1, 16);
                psum[r] += __shfl_xor(psum[r], 2, 16);
                psum[r] += __shfl_xor(psum[r], 4, 16);
                psum[r] += __shfl_xor(psum[r], 8, 16);
                lrow[r] = lrow[r] * corr[r] + psum[r];
            }
#pragma unroll
            for (int t = 0; t < 4; ++t) {
                acc[t][0] *= corr[0]; acc[t][1] *= corr[1];
                acc[t][2] *= corr[2]; acc[t][3] *= corr[3];
            }
#pragma unroll
            for (int st = 0; st < 4; ++st)
#pragma unroll
                for (int r = 0; r < 4; ++r)
                    Pb[w][lg * 4 + r][st * 16 + l15] = (_Float16)s[st][r];
            f16x8 pa0 = *(const f16x8*)&Pb[w][l15][lg * 8];
            f16x8 pa1 = *(const f16x8*)&Pb[w][l15][32 + lg * 8];
            const _Float16* vp = Vt + qkb + (size_t)l15 * SEQ + kt * 64 + lg * 8;
#pragma unroll
            for (int dt = 0; dt < 4; ++dt) {
                f16x8 vb0 = *(const f16x8*)(vp + dt * 16 * SEQ);
                f16x8 vb1 = *(const f16x8*)(vp + dt * 16 * SEQ + 32);
                acc[dt] = __builtin_amdgcn_mfma_f32_16x16x32_f16(pa0, vb0, acc[dt], 0, 0, 0);
                acc[dt] = __builtin_amdgcn_mfma_f32_16x16x32_f16(pa1, vb1, acc[dt], 0, 0, 0);
            }
        }
        _Float16* aop = ao + ((size_t)b_ * SEQ + ibase) * DM + h_ * DH + l15;
#pragma unroll
        for (int r = 0; r < 4; ++r) {
            float inv = 1.f / lrow[r];
#pragma unroll
            for (int dt = 0; dt < 4; ++dt)
                aop[(size_t)r * DM + dt * 16] = (_Float16)(acc[dt][r] * inv);
        }
    }
}

// ---------------------------------------------------------------------------
extern "C" void kernel_launch(void* const* d_in, const int* in_sizes, int n_in,
                              void* d_out, int out_size, void* d_ws, size_t ws_size,
                              hipStream_t stream)
{
    (void)in_sizes; (void)n_in; (void)out_size; (void)ws_size;
    const float* x   = (const float*)d_in[0];
    const float* Wq  = (const float*)d_in[1];
    const float* Wk  = (const float*)d_in[2];
    const float* Wv  = (const float*)d_in[3];
    const float* Wo  = (const float*)d_in[4];
    const float* bo  = (const float*)d_in[5];
    const float* rpb = (const float*)d_in[6];
    float* out = (float*)d_out;

    char* ws = (char*)d_ws;
    _Float16* xh  = (_Float16*)(ws);                  // 8 MB
    _Float16* q   = (_Float16*)(ws + (8u  << 20));    // 8 MB
    _Float16* k   = (_Float16*)(ws + (16u << 20));    // 8 MB
    _Float16* v   = (_Float16*)(ws + (24u << 20));    // 8 MB
    _Float16* vt  = (_Float16*)(ws + (32u << 20));    // 8 MB
    _Float16* aoh = (_Float16*)(ws + (40u << 20));    // 8 MB
    _Float16* wqt = (_Float16*)(ws + (48u << 20));    // 2 MB
    _Float16* wkt = (_Float16*)(ws + (50u << 20));    // 2 MB
    _Float16* wvt = (_Float16*)(ws + (52u << 20));    // 2 MB
    _Float16* wot = (_Float16*)(ws + (54u << 20));    // 2 MB

    cvt_x<<<2048, 256, 0, stream>>>(x, xh, BT * DM / 4);
    cvt_wT<<<dim3(16, 16, 4), 256, 0, stream>>>(Wq, Wk, Wv, Wo, wqt, wkt, wvt, wot);
    gemm_mfma<1><<<dim3(24, 32), 256, 0, stream>>>(xh, wqt, wkt, wvt, q, k, v, nullptr);
    vtranspose<<<dim3(SEQ / 64, BATCH * NH), 256, 0, stream>>>(v, vt);
    attn_mfma<<<dim3(8, BATCH * NH), 256, 0, stream>>>(q, k, vt, rpb, aoh);
    gemm_mfma<0><<<dim3(8, 32), 256, 0, stream>>>(aoh, wot, nullptr, nullptr, out, nullptr, nullptr, bo);
}

// Round 7
// 220.117 us; speedup vs baseline: 8.5233x; 1.1799x over previous
//
#include <hip/hip_runtime.h>
#include <math.h>

// Problem constants (fixed by reference setup_inputs)
#define BATCH 4
#define SEQ   1024
#define DM    1024       // d_model
#define NH    16         // heads
#define DH    64         // head dim
#define BT    (BATCH*SEQ)   // 4096 GEMM rows

typedef _Float16 f16x8 __attribute__((ext_vector_type(8)));
typedef _Float16 f16x4 __attribute__((ext_vector_type(4)));
typedef float    f32x4 __attribute__((ext_vector_type(4)));

// async global->LDS, 16B per lane; LDS dest is wave-uniform base + lane*16
#define GLL16(ldsdst, gsrc) \
  __builtin_amdgcn_global_load_lds((const __attribute__((address_space(1))) void*)(gsrc), \
                                   (__attribute__((address_space(3))) void*)(ldsdst), 16, 0, 0)

// ---------------------------------------------------------------------------
// fp32 -> f16 elementwise (x conversion), float4 -> f16x4
// ---------------------------------------------------------------------------
__global__ __launch_bounds__(256) void cvt_x(const float* __restrict__ x,
                                             _Float16* __restrict__ xh, int nquads)
{
    int i = blockIdx.x * blockDim.x + threadIdx.x;
    for (; i < nquads; i += gridDim.x * blockDim.x) {
        float4 f = ((const float4*)x)[i];
        f16x4 h;
        h[0] = (_Float16)f.x; h[1] = (_Float16)f.y;
        h[2] = (_Float16)f.z; h[3] = (_Float16)f.w;
        ((f16x4*)xh)[i] = h;
    }
}

// ---------------------------------------------------------------------------
// W [1024 k][1024 n] fp32  ->  Wt [1024 n][1024 k] f16   (4 weights, grid.z)
// ---------------------------------------------------------------------------
__global__ __launch_bounds__(256) void cvt_wT(
    const float* __restrict__ W0, const float* __restrict__ W1,
    const float* __restrict__ W2, const float* __restrict__ W3,
    _Float16* __restrict__ T0, _Float16* __restrict__ T1,
    _Float16* __restrict__ T2, _Float16* __restrict__ T3)
{
    __shared__ _Float16 tile[64][72];
    const int z = blockIdx.z;
    const float* W = (z == 0) ? W0 : (z == 1) ? W1 : (z == 2) ? W2 : W3;
    _Float16*    T = (z == 0) ? T0 : (z == 1) ? T1 : (z == 2) ? T2 : T3;
    const int n0 = blockIdx.x * 64;
    const int k0 = blockIdx.y * 64;
    const int tid = threadIdx.x;
#pragma unroll
    for (int p = 0; p < 4; ++p) {
        int r = (tid >> 4) + p * 16;           // k within tile
        int c = (tid & 15) * 4;                // n within tile
        float4 f = *(const float4*)&W[(size_t)(k0 + r) * DM + n0 + c];
        f16x4 h;
        h[0] = (_Float16)f.x; h[1] = (_Float16)f.y;
        h[2] = (_Float16)f.z; h[3] = (_Float16)f.w;
        *(f16x4*)&tile[r][c] = h;
    }
    __syncthreads();
#pragma unroll
    for (int p = 0; p < 2; ++p) {
        int nr = (tid >> 3) + p * 32;          // n within tile
        int kc = (tid & 7) * 8;                // k within tile
        f16x8 vv;
#pragma unroll
        for (int i = 0; i < 8; ++i) vv[i] = tile[kc + i][nr];
        *(f16x8*)&T[(size_t)(n0 + nr) * DM + k0 + kc] = vv;
    }
}

// ---------------------------------------------------------------------------
// f16 MFMA GEMM, m97 structure: 128x128 tile, BK=32, 4 waves, 4x4 16x16x32
// frags per wave, global_load_lds staging (linear LDS), 2-barrier K-loop.
// A [4096][1024] f16 row-major; Bt [N][1024] f16 (transposed weight).
// MODE 1: QKV fused (grid.x = 24: 8 n-tiles each for q,k,v), f16 out in
//         (B,H,T,dh) layout, q scaled by 1/64.
// MODE 0: Wo (grid.x = 8), fp32 out row-major + bias.
// ---------------------------------------------------------------------------
template<int MODE>
__global__ __launch_bounds__(256) void gemm_mfma(
    const _Float16* __restrict__ A,
    const _Float16* __restrict__ B0, const _Float16* __restrict__ B1,
    const _Float16* __restrict__ B2,
    void* __restrict__ o0, void* __restrict__ o1, void* __restrict__ o2,
    const float* __restrict__ bias)
{
    __shared__ _Float16 As[128 * 32];
    __shared__ _Float16 Bs[128 * 32];

    const int tid = threadIdx.x;
    const int w   = tid >> 6;          // wave 0..3
    const int ln  = tid & 63;
    const int l15 = ln & 15;
    const int lg  = ln >> 4;           // 0..3
    const int wr  = w >> 1;            // wave row quadrant
    const int wc  = w & 1;             // wave col quadrant
    const int which = MODE ? (blockIdx.x >> 3) : 0;     // 0:q 1:k 2:v
    const int nl  = (blockIdx.x & 7) * 128;
    const int m0  = blockIdx.y * 128;

    const _Float16* Bt = (which == 0) ? B0 : (which == 1 ? B1 : B2);

    // staging: wave w covers rows w*32..w*32+31 of each tile (2 issues each)
    const int srow = ln >> 2;          // 0..15
    const int scol = (ln & 3) * 8;     // halves
    const _Float16* ga = A  + (size_t)(m0 + w * 32 + srow) * DM + scol;
    const _Float16* gb = Bt + (size_t)(nl + w * 32 + srow) * DM + scol;
    _Float16* la0 = &As[(w * 32 +  0) * 32];
    _Float16* la1 = &As[(w * 32 + 16) * 32];
    _Float16* lb0 = &Bs[(w * 32 +  0) * 32];
    _Float16* lb1 = &Bs[(w * 32 + 16) * 32];

    f32x4 acc[4][4];
#pragma unroll
    for (int i = 0; i < 4; ++i)
#pragma unroll
        for (int j = 0; j < 4; ++j) acc[i][j] = (f32x4){0.f, 0.f, 0.f, 0.f};

    for (int k0 = 0; k0 < DM; k0 += 32) {
        GLL16(la0, ga + k0);
        GLL16(la1, ga + k0 + (size_t)16 * DM);
        GLL16(lb0, gb + k0);
        GLL16(lb1, gb + k0 + (size_t)16 * DM);
        __syncthreads();               // drains vmcnt: tiles staged

        f16x8 af[4], bf[4];
#pragma unroll
        for (int i = 0; i < 4; ++i)
            af[i] = *(const f16x8*)&As[(wr * 64 + i * 16 + l15) * 32 + lg * 8];
#pragma unroll
        for (int j = 0; j < 4; ++j)
            bf[j] = *(const f16x8*)&Bs[(wc * 64 + j * 16 + l15) * 32 + lg * 8];
#pragma unroll
        for (int i = 0; i < 4; ++i)
#pragma unroll
            for (int j = 0; j < 4; ++j)
                acc[i][j] = __builtin_amdgcn_mfma_f32_16x16x32_f16(af[i], bf[j], acc[i][j], 0, 0, 0);
        __syncthreads();               // all reads done before next overwrite
    }

    if (MODE == 1) {
        _Float16* outp = (which == 0) ? (_Float16*)o0
                        : (which == 1) ? (_Float16*)o1 : (_Float16*)o2;
        const float scale = (which == 0) ? 0.015625f : 1.0f;   // Q /= 64
#pragma unroll
        for (int i = 0; i < 4; ++i)
#pragma unroll
            for (int j = 0; j < 4; ++j) {
                int n  = nl + wc * 64 + j * 16 + l15;
                int hh = n >> 6, d = n & 63;
#pragma unroll
                for (int r = 0; r < 4; ++r) {
                    int m  = m0 + wr * 64 + i * 16 + lg * 4 + r;
                    int b_ = m >> 10, t_ = m & 1023;
                    outp[(((size_t)(b_ * NH + hh)) * SEQ + t_) * DH + d] =
                        (_Float16)(acc[i][j][r] * scale);
                }
            }
    } else {
        float* outp = (float*)o0;
#pragma unroll
        for (int i = 0; i < 4; ++i)
#pragma unroll
            for (int j = 0; j < 4; ++j) {
                int n = nl + wc * 64 + j * 16 + l15;
                float bz = bias[n];
#pragma unroll
                for (int r = 0; r < 4; ++r) {
                    int m = m0 + wr * 64 + i * 16 + lg * 4 + r;
                    outp[(size_t)m * DM + n] = acc[i][j][r] + bz;
                }
            }
    }
}

// ---------------------------------------------------------------------------
// V [bh][1024 t][64 d] f16  ->  Vt [bh][64 d][1024 t] f16
// ---------------------------------------------------------------------------
__global__ __launch_bounds__(256) void vtranspose(const _Float16* __restrict__ V,
                                                  _Float16* __restrict__ Vt)
{
    __shared__ _Float16 tile[64][72];
    const int bh = blockIdx.y;
    const int t0 = blockIdx.x * 64;
    const int tid = threadIdx.x;
    const int r = tid >> 3;          // 0..31
    const int c = (tid & 7) * 8;     // 0..56
    const size_t base = (size_t)bh * (SEQ * DH);
#pragma unroll
    for (int p = 0; p < 2; ++p) {
        int row = r + p * 32;
        *(f16x8*)&tile[row][c] = *(const f16x8*)&V[base + (size_t)(t0 + row) * DH + c];
    }
    __syncthreads();
#pragma unroll
    for (int p = 0; p < 2; ++p) {
        int d = r + p * 32;
        f16x8 vv;
#pragma unroll
        for (int i = 0; i < 8; ++i) vv[i] = tile[c + i][d];
        *(f16x8*)&Vt[base + (size_t)d * SEQ + t0 + c] = vv;
    }
}

// ---------------------------------------------------------------------------
// Flash attention, f16 MFMA (16x16x32), causal + rel-pos bias.
// Grid (8 pairs, 64 bh), 512 threads = 8 independent waves.
// Wave w: w<4 -> q-tile pr, rows (w&3)*16; w>=4 -> q-tile 15-pr.
// One 16-row job per wave (was 2 serial) -> 4096 waves, 50% occ cap.
// rpb row staged in LDS (kills per-tile scattered global loads).
// Single barrier at start; waves independent after it.
// ---------------------------------------------------------------------------
__global__ __launch_bounds__(512) void attn_mfma(
    const _Float16* __restrict__ Q,   // [bh][1024][64], pre-scaled by 1/64
    const _Float16* __restrict__ K,   // [bh][1024][64]
    const _Float16* __restrict__ Vt,  // [bh][64][1024]
    const float* __restrict__ rpb,    // [16][1024]
    _Float16* __restrict__ ao)        // [b][t][h*64+d] f16
{
    const int pr  = blockIdx.x;       // 0..7
    const int bh  = blockIdx.y;       // 0..63
    const int b_  = bh >> 4;
    const int h_  = bh & 15;
    const int tid = threadIdx.x;
    const int w   = tid >> 6;         // wave 0..7
    const int ln  = tid & 63;
    const int l15 = ln & 15;
    const int lg  = ln >> 4;          // 0..3

    __shared__ _Float16 Pb[8][16][72];   // per-wave P buffer
    __shared__ float rpb_s[SEQ];

    // stage this head's rpb row (512 threads x 2 floats)
    *(float2*)&rpb_s[tid * 2] = *(const float2*)&rpb[h_ * SEQ + tid * 2];
    __syncthreads();                  // only barrier in the kernel

    const size_t qkb = (size_t)bh * (SEQ * DH);
    const int qt  = (w < 4) ? pr : (15 - pr);
    const int qr0 = qt * 64 + (w & 3) * 16;

    f16x8 qa0, qa1;
    {
        const _Float16* qp = Q + qkb + (size_t)(qr0 + l15) * DH + lg * 8;
        qa0 = *(const f16x8*)qp;
        qa1 = *(const f16x8*)(qp + 32);
    }
    f32x4 acc[4];
    float mrow[4], lrow[4];
#pragma unroll
    for (int t = 0; t < 4; ++t) {
        acc[t] = (f32x4){0.f, 0.f, 0.f, 0.f};
        mrow[t] = -INFINITY;
        lrow[t] = 0.f;
    }
    const int ibase = qr0 + lg * 4;   // q row for reg r is ibase + r

#pragma unroll 1
    for (int kt = 0; kt <= qt; ++kt) {
        // ---- S = Q K^T (4 kv sub-tiles of 16) ----
        const _Float16* kp = K + qkb + (size_t)(kt * 64 + l15) * DH + lg * 8;
        f32x4 s[4];
#pragma unroll
        for (int st = 0; st < 4; ++st) {
            f16x8 kb0 = *(const f16x8*)(kp + st * 16 * DH);
            f16x8 kb1 = *(const f16x8*)(kp + st * 16 * DH + 32);
            f32x4 z = (f32x4){0.f, 0.f, 0.f, 0.f};
            z = __builtin_amdgcn_mfma_f32_16x16x32_f16(qa0, kb0, z, 0, 0, 0);
            z = __builtin_amdgcn_mfma_f32_16x16x32_f16(qa1, kb1, z, 0, 0, 0);
            s[st] = z;
        }
        // ---- bias + causal mask + tile max ----
        // idx = 1023 - i + j ; masked <=> idx > 1023 (j > i). idx >= 0 always.
        const int bidx = 1023 - ibase + l15 + kt * 64;
        float tm[4] = {-INFINITY, -INFINITY, -INFINITY, -INFINITY};
#pragma unroll
        for (int st = 0; st < 4; ++st)
#pragma unroll
            for (int r = 0; r < 4; ++r) {
                int idx = bidx + st * 16 - r;
                float bv = rpb_s[idx <= 1023 ? idx : 1023];
                float val = (idx <= 1023) ? fmaf(bv, 0.015625f, s[st][r]) : -INFINITY;
                s[st][r] = val;
                tm[r] = fmaxf(tm[r], val);
            }
        // ---- online softmax (reduce over 16 kv lanes) ----
#pragma unroll
        for (int r = 0; r < 4; ++r) {
            tm[r] = fmaxf(tm[r], __shfl_xor(tm[r], 1, 16));
            tm[r] = fmaxf(tm[r], __shfl_xor(tm[r], 2, 16));
            tm[r] = fmaxf(tm[r], __shfl_xor(tm[r], 4, 16));
            tm[r] = fmaxf(tm[r], __shfl_xor(tm[r], 8, 16));
        }
        float corr[4], psum[4];
#pragma unroll
        for (int r = 0; r < 4; ++r) {
            float mn = fmaxf(mrow[r], tm[r]);
            corr[r]  = __expf(mrow[r] - mn);
            mrow[r]  = mn;
            psum[r]  = 0.f;
        }
#pragma unroll
        for (int st = 0; st < 4; ++st)
#pragma unroll
            for (int r = 0; r < 4; ++r) {
                float p = __expf(s[st][r] - mrow[r]);
                s[st][r] = p;
                psum[r] += p;
            }
#pragma unroll
        for (int r = 0; r < 4; ++r) {
            psum[r] += __shfl_xor(psum[r], 1, 16);
            psum[r] += __shfl_xor(psum[r], 2, 16);
            psum[r] += __shfl_xor(psum[r], 4, 16);
            psum[r] += __shfl_xor(psum[r], 8, 16);
            lrow[r] = lrow[r] * corr[r] + psum[r];
        }
#pragma unroll
        for (int t = 0; t < 4; ++t) {
            acc[t][0] *= corr[0]; acc[t][1] *= corr[1];
            acc[t][2] *= corr[2]; acc[t][3] *= corr[3];
        }
        // ---- P -> per-wave LDS (S layout -> A-frag layout) ----
#pragma unroll
        for (int st = 0; st < 4; ++st)
#pragma unroll
            for (int r = 0; r < 4; ++r)
                Pb[w][lg * 4 + r][st * 16 + l15] = (_Float16)s[st][r];
        // P written/read by the same wave -> no barrier needed
        f16x8 pa0 = *(const f16x8*)&Pb[w][l15][lg * 8];
        f16x8 pa1 = *(const f16x8*)&Pb[w][l15][32 + lg * 8];
        const _Float16* vp = Vt + qkb + (size_t)l15 * SEQ + kt * 64 + lg * 8;
#pragma unroll
        for (int dt = 0; dt < 4; ++dt) {
            f16x8 vb0 = *(const f16x8*)(vp + dt * 16 * SEQ);
            f16x8 vb1 = *(const f16x8*)(vp + dt * 16 * SEQ + 32);
            acc[dt] = __builtin_amdgcn_mfma_f32_16x16x32_f16(pa0, vb0, acc[dt], 0, 0, 0);
            acc[dt] = __builtin_amdgcn_mfma_f32_16x16x32_f16(pa1, vb1, acc[dt], 0, 0, 0);
        }
    }
    // ---- epilogue ----
    _Float16* aop = ao + ((size_t)b_ * SEQ + ibase) * DM + h_ * DH + l15;
#pragma unroll
    for (int r = 0; r < 4; ++r) {
        float inv = 1.f / lrow[r];
#pragma unroll
        for (int dt = 0; dt < 4; ++dt)
            aop[(size_t)r * DM + dt * 16] = (_Float16)(acc[dt][r] * inv);
    }
}

// ---------------------------------------------------------------------------
extern "C" void kernel_launch(void* const* d_in, const int* in_sizes, int n_in,
                              void* d_out, int out_size, void* d_ws, size_t ws_size,
                              hipStream_t stream)
{
    (void)in_sizes; (void)n_in; (void)out_size; (void)ws_size;
    const float* x   = (const float*)d_in[0];
    const float* Wq  = (const float*)d_in[1];
    const float* Wk  = (const float*)d_in[2];
    const float* Wv  = (const float*)d_in[3];
    const float* Wo  = (const float*)d_in[4];
    const float* bo  = (const float*)d_in[5];
    const float* rpb = (const float*)d_in[6];
    float* out = (float*)d_out;

    char* ws = (char*)d_ws;
    _Float16* xh  = (_Float16*)(ws);                  // 8 MB
    _Float16* q   = (_Float16*)(ws + (8u  << 20));    // 8 MB
    _Float16* k   = (_Float16*)(ws + (16u << 20));    // 8 MB
    _Float16* v   = (_Float16*)(ws + (24u << 20));    // 8 MB
    _Float16* vt  = (_Float16*)(ws + (32u << 20));    // 8 MB
    _Float16* aoh = (_Float16*)(ws + (40u << 20));    // 8 MB
    _Float16* wqt = (_Float16*)(ws + (48u << 20));    // 2 MB
    _Float16* wkt = (_Float16*)(ws + (50u << 20));    // 2 MB
    _Float16* wvt = (_Float16*)(ws + (52u << 20));    // 2 MB
    _Float16* wot = (_Float16*)(ws + (54u << 20));    // 2 MB

    cvt_x<<<2048, 256, 0, stream>>>(x, xh, BT * DM / 4);
    cvt_wT<<<dim3(16, 16, 4), 256, 0, stream>>>(Wq, Wk, Wv, Wo, wqt, wkt, wvt, wot);
    gemm_mfma<1><<<dim3(24, 32), 256, 0, stream>>>(xh, wqt, wkt, wvt, q, k, v, nullptr);
    vtranspose<<<dim3(SEQ / 64, BATCH * NH), 256, 0, stream>>>(v, vt);
    attn_mfma<<<dim3(8, BATCH * NH), 512, 0, stream>>>(q, k, vt, rpb, aoh);
    gemm_mfma<0><<<dim3(8, 32), 256, 0, stream>>>(aoh, wot, nullptr, nullptr, out, nullptr, nullptr, bo);
}